// Round 8
// baseline (298.460 us; speedup 1.0000x reference)
//
#include <hip/hip_runtime.h>
#include <hip/hip_fp16.h>

#define B_ROWS   16384
#define K_NB     64
#define U_ROWS   100000
#define D_DIM    256
#define TWO_D    512
#define R_BLK    8          // rows per block
#define THREADS  256

typedef float f32x2_t __attribute__((ext_vector_type(2)));

#if __has_builtin(__builtin_amdgcn_cvt_pk_f32_fp8) && __has_builtin(__builtin_amdgcn_cvt_pk_fp8_f32)
#define FP8_HW 1
#else
#define FP8_HW 0
#include <hip/hip_fp8.h>
#endif

__device__ __forceinline__ unsigned pack4_fp8(float a, float b, float c, float d) {
#if FP8_HW
    int v = 0;
    v = __builtin_amdgcn_cvt_pk_fp8_f32(a, b, v, false);   // bytes 0-1
    v = __builtin_amdgcn_cvt_pk_fp8_f32(c, d, v, true);    // bytes 2-3
    return (unsigned)v;
#else
    __hip_fp8_e4m3 x0(a), x1(b), x2(c), x3(d);
    return (unsigned)x0.__x | ((unsigned)x1.__x << 8)
         | ((unsigned)x2.__x << 16) | ((unsigned)x3.__x << 24);
#endif
}

__device__ __forceinline__ float4 unpack4_fp8(unsigned u) {
#if FP8_HW
    const f32x2_t lo = __builtin_amdgcn_cvt_pk_f32_fp8((int)u, false);
    const f32x2_t hi = __builtin_amdgcn_cvt_pk_f32_fp8((int)u, true);
    return make_float4(lo[0], lo[1], hi[0], hi[1]);
#else
    __hip_fp8_e4m3 x0, x1, x2, x3;
    x0.__x = u & 0xff; x1.__x = (u >> 8) & 0xff;
    x2.__x = (u >> 16) & 0xff; x3.__x = (u >> 24) & 0xff;
    return make_float4((float)x0, (float)x1, (float)x2, (float)x3);
#endif
}

// ============ pre-pass: u2e fp32 -> fp8 e4m3 (row-major [U][256]) ============
__global__ __launch_bounds__(256)
void cvt_u2e_fp8(const float* __restrict__ src, uint2* __restrict__ dst, int n8) {
    const int i = blockIdx.x * 256 + threadIdx.x;
    if (i >= n8) return;
    const float4 a = ((const float4*)src)[2 * i];
    const float4 b = ((const float4*)src)[2 * i + 1];
    uint2 o;
    o.x = pack4_fp8(a.x, a.y, a.z, a.w);
    o.y = pack4_fp8(b.x, b.y, b.z, b.w);
    dst[i] = o;
}

// ============ main fused kernel: fully specialized waves ============
// waves 0-1: pure fp8 gather (scalar index loads from global, no LDS staging,
// no entry barrier). waves 2-3: preamble (self/v/bias, overlapped with the
// gather) + W^T v matvec + epilogue dot. Barriers are UNIFORM: both
// __syncthreads() sit at top level, executed by all waves (r7's in-branch
// barriers are formally UB and may have hung the container).
__global__ __launch_bounds__(THREADS, 4)
void easyrec_fused_q(const int* __restrict__ nodes_u,
                     const int* __restrict__ nodes_v,
                     const int* __restrict__ neighbors,
                     const int* __restrict__ neighbor_counts,
                     const float* __restrict__ u2e,
                     const unsigned char* __restrict__ u8,  // fp8 copy of u2e
                     const float* __restrict__ v2e,
                     const float* __restrict__ W,     // [D, 2D] row-major
                     const float* __restrict__ bias,  // [D]
                     float* __restrict__ out)         // [B]
{
    __shared__ __align__(16) float cat_lds[R_BLK][TWO_D];   // 16 KB: [self | nmean]
    __shared__ float red_lds[R_BLK * 2];
    __shared__ float selfdot_lds[R_BLK];
    __shared__ float bdot_lds[R_BLK];

    const int t    = threadIdx.x;
    const int wave = t >> 6;
    const int lane = t & 63;
    const int row0 = blockIdx.x * R_BLK;

    float4 acc4[R_BLK];   // matvec accumulators (waves 2-3); live across barrier 1

    if (wave < 2) {
        // ================= GATHER role (waves 0-1): pure gather =================
        const unsigned colq = (unsigned)lane * 4u;

#define LOADQ8(P, BASE, KK)                                                         \
    const int4 P##ia = *(const int4*)&neighbors[(BASE) + (KK)];                     \
    const int4 P##ib = *(const int4*)&neighbors[(BASE) + (KK) + 4];                 \
    const unsigned P##n0 = *(const unsigned*)(u8 + (((unsigned)P##ia.x) << 8) + colq); \
    const unsigned P##n1 = *(const unsigned*)(u8 + (((unsigned)P##ia.y) << 8) + colq); \
    const unsigned P##n2 = *(const unsigned*)(u8 + (((unsigned)P##ia.z) << 8) + colq); \
    const unsigned P##n3 = *(const unsigned*)(u8 + (((unsigned)P##ia.w) << 8) + colq); \
    const unsigned P##n4 = *(const unsigned*)(u8 + (((unsigned)P##ib.x) << 8) + colq); \
    const unsigned P##n5 = *(const unsigned*)(u8 + (((unsigned)P##ib.y) << 8) + colq); \
    const unsigned P##n6 = *(const unsigned*)(u8 + (((unsigned)P##ib.z) << 8) + colq); \
    const unsigned P##n7 = *(const unsigned*)(u8 + (((unsigned)P##ib.w) << 8) + colq);

#define ACCQ1(P, N, ACC, M)                                                         \
    {                                                                               \
        const float4 f = unpack4_fp8(P##N);                                         \
        ACC.x += (M) * f.x; ACC.y += (M) * f.y;                                     \
        ACC.z += (M) * f.z; ACC.w += (M) * f.w;                                     \
    }

#define ACCQ8(P, ACC, CNT, KK)                                                      \
    {                                                                               \
        const float m0 = ((KK) + 0 < (CNT)) ? 1.f : 0.f;                            \
        const float m1 = ((KK) + 1 < (CNT)) ? 1.f : 0.f;                            \
        const float m2 = ((KK) + 2 < (CNT)) ? 1.f : 0.f;                            \
        const float m3 = ((KK) + 3 < (CNT)) ? 1.f : 0.f;                            \
        const float m4 = ((KK) + 4 < (CNT)) ? 1.f : 0.f;                            \
        const float m5 = ((KK) + 5 < (CNT)) ? 1.f : 0.f;                            \
        const float m6 = ((KK) + 6 < (CNT)) ? 1.f : 0.f;                            \
        const float m7 = ((KK) + 7 < (CNT)) ? 1.f : 0.f;                            \
        ACCQ1(P, n0, ACC, m0) ACCQ1(P, n1, ACC, m1)                                 \
        ACCQ1(P, n2, ACC, m2) ACCQ1(P, n3, ACC, m3)                                 \
        ACCQ1(P, n4, ACC, m4) ACCQ1(P, n5, ACC, m5)                                 \
        ACCQ1(P, n6, ACC, m6) ACCQ1(P, n7, ACC, m7)                                 \
    }

        // two dual-row pairs: wave0 -> (0,4),(1,5); wave1 -> (2,6),(3,7)
        for (int pp = 0; pp < 2; ++pp) {
            const int rA = wave * 2 + pp;
            const int rB = rA + 4;
            const int cntA = __builtin_amdgcn_readfirstlane(neighbor_counts[row0 + rA]);
            const int cntB = __builtin_amdgcn_readfirstlane(neighbor_counts[row0 + rB]);
            const int itA = (cntA + 7) >> 3;
            const int itB = (cntB + 7) >> 3;
            const int itMin = itA < itB ? itA : itB;
            const int itMax = itA > itB ? itA : itB;
            const int baseA = (row0 + rA) * K_NB;
            const int baseB = (row0 + rB) * K_NB;

            float4 accA = make_float4(0.f, 0.f, 0.f, 0.f);
            float4 accB = make_float4(0.f, 0.f, 0.f, 0.f);

            for (int i = 0; i < itMin; ++i) {
                const int k = i << 3;
                LOADQ8(A, baseA, k)
                LOADQ8(B, baseB, k)
                ACCQ8(A, accA, cntA, k)
                ACCQ8(B, accB, cntB, k)
            }
            if (itMin < itMax) {
                const bool Along = itA > itB;
                const int  cntL  = Along ? cntA : cntB;
                const int  baseL = Along ? baseA : baseB;
                float4 accL = make_float4(0.f, 0.f, 0.f, 0.f);
                for (int i = itMin; i < itMax; ++i) {
                    const int k = i << 3;
                    LOADQ8(L, baseL, k)
                    ACCQ8(L, accL, cntL, k)
                }
                if (Along) {
                    accA.x += accL.x; accA.y += accL.y; accA.z += accL.z; accA.w += accL.w;
                } else {
                    accB.x += accL.x; accB.y += accL.y; accB.z += accL.z; accB.w += accL.w;
                }
            }

            const float invA = 1.0f / (float)(cntA > 0 ? cntA : 1);
            const float invB = 1.0f / (float)(cntB > 0 ? cntB : 1);
            *(float4*)(&cat_lds[rA][D_DIM + 4 * lane]) =
                make_float4(accA.x * invA, accA.y * invA, accA.z * invA, accA.w * invA);
            *(float4*)(&cat_lds[rB][D_DIM + 4 * lane]) =
                make_float4(accB.x * invB, accB.y * invB, accB.z * invB, accB.w * invB);
        }
#undef LOADQ8
#undef ACCQ8
#undef ACCQ1
    } else {
        // ====== PREAMBLE + MATVEC role (waves 2-3) ======
        const unsigned colb = (unsigned)lane * 16u;

        // preamble: 4 rows per wave — random self/v lines overlap the gather now.
        {
            const float4 b4 = *(const float4*)((const char*)bias + colb);
            const int rbase = (wave - 2) * 4;
            #pragma unroll
            for (int rr = 0; rr < 4; ++rr) {
                const int r   = rbase + rr;
                const int row = row0 + r;
                const int nu  = __builtin_amdgcn_readfirstlane(nodes_u[row]);
                const int nv  = __builtin_amdgcn_readfirstlane(nodes_v[row]);
                const float4 self4 = *(const float4*)((const char*)u2e + (((size_t)nu) << 10) + colb);
                const float4 v4    = *(const float4*)((const char*)v2e + (((size_t)nv) << 10) + colb);
                *(float4*)(&cat_lds[r][4 * lane]) = self4;
                float sv = self4.x * v4.x + self4.y * v4.y + self4.z * v4.z + self4.w * v4.w;
                float bv = b4.x * v4.x + b4.y * v4.y + b4.z * v4.z + b4.w * v4.w;
                #pragma unroll
                for (int off = 32; off > 0; off >>= 1) {
                    sv += __shfl_xor(sv, off, 64);
                    bv += __shfl_xor(bv, off, 64);
                }
                if (lane == 0) { selfdot_lds[r] = sv; bdot_lds[r] = bv; }
            }
        }

        // matvec: t_j = sum_d W[d, j] * v[d]; thread tm owns j = 4*tm .. 4*tm+3.
        const int tm = t - 128;      // 0..127
        unsigned voff[R_BLK];
        #pragma unroll
        for (int r = 0; r < R_BLK; ++r) {
            const int nv = __builtin_amdgcn_readfirstlane(nodes_v[row0 + r]);
            voff[r] = ((unsigned)nv) << 10;
        }

        #pragma unroll
        for (int r = 0; r < R_BLK; ++r) acc4[r] = make_float4(0.f, 0.f, 0.f, 0.f);

        const unsigned tb16 = (unsigned)tm * 16u;
        for (int d = 0; d < D_DIM; d += 4) {
            float4 vq[R_BLK];
            #pragma unroll
            for (int r = 0; r < R_BLK; ++r)
                vq[r] = *(const float4*)((const char*)v2e + voff[r] + (unsigned)d * 4u);

            #pragma unroll
            for (int dd = 0; dd < 4; ++dd) {
                const float4 w4 = *(const float4*)((const char*)W + (((unsigned)(d + dd)) << 11) + tb16);
                #pragma unroll
                for (int r = 0; r < R_BLK; ++r) {
                    const float vs = (dd == 0) ? vq[r].x : (dd == 1) ? vq[r].y
                                   : (dd == 2) ? vq[r].z : vq[r].w;
                    acc4[r].x += w4.x * vs;
                    acc4[r].y += w4.y * vs;
                    acc4[r].z += w4.z * vs;
                    acc4[r].w += w4.w * vs;
                }
            }
        }
    }

    __syncthreads();   // UNIFORM barrier 1: nmean + self + t all published

    if (wave >= 2) {
        // epilogue: wave2 covers j<256 (self half), wave3 j>=256 (nmean half)
        const int tm = t - 128;
        #pragma unroll
        for (int r = 0; r < R_BLK; ++r) {
            const float4 c4 = *(const float4*)(&cat_lds[r][4 * tm]);
            float p = c4.x * acc4[r].x + c4.y * acc4[r].y
                    + c4.z * acc4[r].z + c4.w * acc4[r].w;
            #pragma unroll
            for (int off = 32; off > 0; off >>= 1) p += __shfl_xor(p, off, 64);
            if (lane == 0) red_lds[r * 2 + (wave - 2)] = p;
        }
    }

    __syncthreads();   // UNIFORM barrier 2: red_lds published

    if (t < R_BLK) {
        const int row = row0 + t;
        const int cnt = neighbor_counts[row];
        float s;
        if (cnt > 0) {
            s = red_lds[t * 2 + 0] + red_lds[t * 2 + 1] + bdot_lds[t];
        } else {
            s = selfdot_lds[t];
        }
        out[row] = s;
    }
}

// ============ fp32 fallback (ws too small): round-0 proven kernel ============
__global__ __launch_bounds__(THREADS, 4)
void easyrec_fused_f(const int* __restrict__ nodes_u,
                     const int* __restrict__ nodes_v,
                     const int* __restrict__ neighbors,
                     const int* __restrict__ neighbor_counts,
                     const float* __restrict__ u2e,
                     const float* __restrict__ v2e,
                     const float* __restrict__ W,
                     const float* __restrict__ bias,
                     float* __restrict__ out)
{
    __shared__ __align__(16) int   nbr_lds[R_BLK * K_NB];
    __shared__ __align__(16) float cat_lds[R_BLK][TWO_D];
    __shared__ float red_lds[R_BLK * 4];
    __shared__ float selfdot_lds[R_BLK];
    __shared__ float bdot_lds[R_BLK];

    const int t    = threadIdx.x;
    const int wave = t >> 6;
    const int lane = t & 63;
    const int row0 = blockIdx.x * R_BLK;

    nbr_lds[t]           = neighbors[(size_t)row0 * K_NB + t];
    nbr_lds[t + THREADS] = neighbors[(size_t)row0 * K_NB + t + THREADS];
    __syncthreads();

    for (int rr = 0; rr < 2; ++rr) {
        const int r   = wave + rr * 4;
        const int row = row0 + r;
        const int nu  = __builtin_amdgcn_readfirstlane(nodes_u[row]);
        const int nv  = __builtin_amdgcn_readfirstlane(nodes_v[row]);
        const int cnt = __builtin_amdgcn_readfirstlane(neighbor_counts[row]);

        const float4 self4 = *(const float4*)(u2e + (size_t)nu * D_DIM + 4 * lane);
        const float4 v4    = *(const float4*)(v2e + (size_t)nv * D_DIM + 4 * lane);
        const float4 b4    = *(const float4*)(bias + 4 * lane);

        float4 acc = make_float4(0.f, 0.f, 0.f, 0.f);
        const int base = r * K_NB;
        const int kmax = (cnt + 7) & ~7;
        for (int k = 0; k < kmax; k += 8) {
            const int4 ia = *(const int4*)&nbr_lds[base + k];
            const int4 ib = *(const int4*)&nbr_lds[base + k + 4];
            const float4 n0 = *(const float4*)(u2e + (size_t)ia.x * D_DIM + 4 * lane);
            const float4 n1 = *(const float4*)(u2e + (size_t)ia.y * D_DIM + 4 * lane);
            const float4 n2 = *(const float4*)(u2e + (size_t)ia.z * D_DIM + 4 * lane);
            const float4 n3 = *(const float4*)(u2e + (size_t)ia.w * D_DIM + 4 * lane);
            const float4 n4 = *(const float4*)(u2e + (size_t)ib.x * D_DIM + 4 * lane);
            const float4 n5 = *(const float4*)(u2e + (size_t)ib.y * D_DIM + 4 * lane);
            const float4 n6 = *(const float4*)(u2e + (size_t)ib.z * D_DIM + 4 * lane);
            const float4 n7 = *(const float4*)(u2e + (size_t)ib.w * D_DIM + 4 * lane);
            const float m0 = (k + 0 < cnt) ? 1.f : 0.f;
            const float m1 = (k + 1 < cnt) ? 1.f : 0.f;
            const float m2 = (k + 2 < cnt) ? 1.f : 0.f;
            const float m3 = (k + 3 < cnt) ? 1.f : 0.f;
            const float m4 = (k + 4 < cnt) ? 1.f : 0.f;
            const float m5 = (k + 5 < cnt) ? 1.f : 0.f;
            const float m6 = (k + 6 < cnt) ? 1.f : 0.f;
            const float m7 = (k + 7 < cnt) ? 1.f : 0.f;
            acc.x += n0.x*m0 + n1.x*m1 + n2.x*m2 + n3.x*m3 + n4.x*m4 + n5.x*m5 + n6.x*m6 + n7.x*m7;
            acc.y += n0.y*m0 + n1.y*m1 + n2.y*m2 + n3.y*m3 + n4.y*m4 + n5.y*m5 + n6.y*m6 + n7.y*m7;
            acc.z += n0.z*m0 + n1.z*m1 + n2.z*m2 + n3.z*m3 + n4.z*m4 + n5.z*m5 + n6.z*m6 + n7.z*m7;
            acc.w += n0.w*m0 + n1.w*m1 + n2.w*m2 + n3.w*m3 + n4.w*m4 + n5.w*m5 + n6.w*m6 + n7.w*m7;
        }
        const float inv = 1.0f / (float)(cnt > 0 ? cnt : 1);
        *(float4*)(&cat_lds[r][4 * lane])         = self4;
        *(float4*)(&cat_lds[r][D_DIM + 4 * lane]) =
            make_float4(acc.x * inv, acc.y * inv, acc.z * inv, acc.w * inv);

        float sv = self4.x * v4.x + self4.y * v4.y + self4.z * v4.z + self4.w * v4.w;
        float bv = b4.x * v4.x + b4.y * v4.y + b4.z * v4.z + b4.w * v4.w;
        #pragma unroll
        for (int off = 32; off > 0; off >>= 1) {
            sv += __shfl_xor(sv, off, 64);
            bv += __shfl_xor(bv, off, 64);
        }
        if (lane == 0) { selfdot_lds[r] = sv; bdot_lds[r] = bv; }
    }
    __syncthreads();

    const float* vrow[R_BLK];
    #pragma unroll
    for (int r = 0; r < R_BLK; ++r) {
        const int nv = __builtin_amdgcn_readfirstlane(nodes_v[row0 + r]);
        vrow[r] = v2e + (size_t)nv * D_DIM;
    }

    float2 acc2[R_BLK];
    #pragma unroll
    for (int r = 0; r < R_BLK; ++r) acc2[r] = make_float2(0.f, 0.f);

    for (int d = 0; d < D_DIM; d += 4) {
        float4 vq[R_BLK];
        #pragma unroll
        for (int r = 0; r < R_BLK; ++r) vq[r] = *(const float4*)(vrow[r] + d);
        #pragma unroll
        for (int dd = 0; dd < 4; ++dd) {
            const float2 wq = *(const float2*)(W + (size_t)(d + dd) * TWO_D + 2 * t);
            #pragma unroll
            for (int r = 0; r < R_BLK; ++r) {
                const float vs = (dd == 0) ? vq[r].x : (dd == 1) ? vq[r].y
                               : (dd == 2) ? vq[r].z : vq[r].w;
                acc2[r].x += wq.x * vs;
                acc2[r].y += wq.y * vs;
            }
        }
    }

    #pragma unroll
    for (int r = 0; r < R_BLK; ++r) {
        const float2 c2 = *(const float2*)(&cat_lds[r][2 * t]);
        float p = c2.x * acc2[r].x + c2.y * acc2[r].y;
        #pragma unroll
        for (int off = 32; off > 0; off >>= 1) p += __shfl_xor(p, off, 64);
        if (lane == 0) red_lds[r * 4 + wave] = p;
    }
    __syncthreads();

    if (t < R_BLK) {
        const int row = row0 + t;
        const int cnt = neighbor_counts[row];
        float s;
        if (cnt > 0) {
            s = red_lds[t * 4 + 0] + red_lds[t * 4 + 1]
              + red_lds[t * 4 + 2] + red_lds[t * 4 + 3] + bdot_lds[t];
        } else {
            s = selfdot_lds[t];
        }
        out[row] = s;
    }
}

extern "C" void kernel_launch(void* const* d_in, const int* in_sizes, int n_in,
                              void* d_out, int out_size, void* d_ws, size_t ws_size,
                              hipStream_t stream) {
    const int*   nodes_u         = (const int*)d_in[0];
    const int*   nodes_v         = (const int*)d_in[1];
    const int*   neighbors       = (const int*)d_in[2];
    const int*   neighbor_counts = (const int*)d_in[3];
    const float* u2e             = (const float*)d_in[4];
    const float* v2e             = (const float*)d_in[5];
    const float* W               = (const float*)d_in[6];
    const float* bias            = (const float*)d_in[7];
    float*       out             = (float*)d_out;

    const size_t need = (size_t)U_ROWS * D_DIM;   // 25.6 MB fp8 table
    const int blocks = B_ROWS / R_BLK;            // 2048

    if (d_ws != nullptr && ws_size >= need) {
        unsigned char* u8 = (unsigned char*)d_ws;
        const int n8 = U_ROWS * D_DIM / 8;        // 3.2M threads, 8 elems each
        const int cblocks = (n8 + 255) / 256;
        cvt_u2e_fp8<<<cblocks, 256, 0, stream>>>(u2e, (uint2*)u8, n8);
        easyrec_fused_q<<<blocks, THREADS, 0, stream>>>(
            nodes_u, nodes_v, neighbors, neighbor_counts, u2e, u8, v2e, W, bias, out);
    } else {
        easyrec_fused_f<<<blocks, THREADS, 0, stream>>>(
            nodes_u, nodes_v, neighbors, neighbor_counts, u2e, v2e, W, bias, out);
    }
}